// Round 10
// baseline (251.183 us; speedup 1.0000x reference)
//
#include <hip/hip_runtime.h>

// ---------------------------------------------------------------------------
// SAGE-GCN LSTM, N=1024, J=24, D=64.  R10 = dependency-free phases:
//  mono: 512 blocks (2/CU) x 512 thr (8 waves), 2 elems/block, 24 cells.
//  Key ideas vs R9:
//   - chunk ownership: epi wave w writes d-chunk w; agg for chunk w runs on
//     wave w -> epi->agg is same-wave in-order LDS, NO barrier, XH single-buf.
//   - deferred epilogue (2 acc sets): P1 {MFMA(e0,s) || epi(e1,s-1)->agg(e1,s)}
//     P2 {MFMA(e1,s) || epi(e0,s)->agg(e0,s+1)} - all streams independent.
//   - M-remap d7 = u + 4*hi -> epi writes 2 x b64 LDS + 1 x b64 global.
//  State x/h and agg in MFMA B-frag layout (fp16), W per-wave in 64 VGPRs.
//  dec: fp16 MFMA, 4-wave K-split + LDS reduce.  prep: weight packing.
// ---------------------------------------------------------------------------

typedef _Float16 f16x8 __attribute__((ext_vector_type(8)));
typedef float f32x16 __attribute__((ext_vector_type(16)));

// neighbor table with sentinel 24 (zero pad row) instead of -1: always 5 reads
__constant__ int c_nbr2[24][5] = {
  {0,1,2,3,24},  {1,0,4,24,24}, {2,0,5,24,24}, {3,0,6,24,24},
  {4,1,7,24,24}, {5,2,8,24,24}, {6,3,9,24,24}, {7,4,10,24,24},
  {8,5,11,24,24},{9,6,12,13,14},{10,7,24,24,24},{11,8,24,24,24},
  {12,9,15,24,24},{13,9,16,24,24},{14,9,17,24,24},{15,12,24,24,24},
  {16,13,18,24,24},{17,14,19,24,24},{18,16,20,24,24},{19,17,21,24,24},
  {20,18,22,24,24},{21,19,23,24,24},{22,20,24,24,24},{23,21,24,24,24}
};
__constant__ float c_invdeg[24] = {
  0.25f, 1.f/3.f, 1.f/3.f, 1.f/3.f, 1.f/3.f, 1.f/3.f, 1.f/3.f, 1.f/3.f,
  1.f/3.f, 0.2f, 0.5f, 0.5f, 1.f/3.f, 1.f/3.f, 1.f/3.f, 0.5f,
  1.f/3.f, 1.f/3.f, 1.f/3.f, 1.f/3.f, 1.f/3.f, 1.f/3.f, 0.5f, 0.5f
};

__device__ __forceinline__ unsigned short f2h(float f) {
  _Float16 h = (_Float16)f;
  return __builtin_bit_cast(unsigned short, h);
}
__device__ __forceinline__ unsigned pk2h(float a, float b) {
  return (unsigned)f2h(a) | ((unsigned)f2h(b) << 16);
}
__device__ __forceinline__ unsigned pkrtz(float lo, float hi) {  // 1 inst
  unsigned r;
  asm("v_cvt_pkrtz_f16_f32 %0, %1, %2" : "=v"(r) : "v"(lo), "v"(hi));
  return r;
}
__device__ __forceinline__ float h2f_lo(unsigned u) {
  return (float)__builtin_bit_cast(_Float16, (unsigned short)(u & 0xffff));
}
__device__ __forceinline__ float h2f_hi(unsigned u) {
  return (float)__builtin_bit_cast(_Float16, (unsigned short)(u >> 16));
}
__device__ __forceinline__ float sigm_(float x) {
  return __builtin_amdgcn_rcpf(1.0f + __expf(-x));
}
__device__ __forceinline__ float tanh_(float x) {
  return 1.0f - 2.0f * __builtin_amdgcn_rcpf(1.0f + __expf(2.0f * x));
}

// ---------------------------------------------------------------------------
// prep: Wfrag (fp16, A-frag layout), biasv f32, Bdec fp16.
//  m32 -> (g, d): g = m32 & 3; tq = m32>>2; doff = (tq>>1) + 4*(tq&1);
//  d = mt*8 + doff.  (So acc reg r, lane-hi -> gate r&3 at d7 = (r>>2)+4*hi,
//  making the 4 u-values of a thread CONTIGUOUS in d -> b64 epi writes.)
//  k = t*16 + (lane>>5)*8 + i; q=k>>6: q0 Wl[2g], q1 Wr[2g], q2 Wl[2g+1], q3 Wr[2g+1]
// ---------------------------------------------------------------------------
__global__ void prep5_kernel(const float* __restrict__ sWl, const float* __restrict__ sbl,
                             const float* __restrict__ sWr, const float* __restrict__ gb,
                             const float* __restrict__ dW,
                             unsigned short* __restrict__ Wfrag,
                             float* __restrict__ biasv,
                             unsigned short* __restrict__ Bdec)
{
  int id = blockIdx.x * 256 + threadIdx.x;          // 213248 total
  if (id < 65536) {                                  // Wfrag [mt][t][lane][8]
    int i = id & 7, l = (id >> 3) & 63, t = (id >> 9) & 15, mt = id >> 13;
    int m32 = l & 31;
    int g = m32 & 3, tq = m32 >> 2;
    int d = mt * 8 + (tq >> 1) + 4 * (tq & 1);
    int k = t * 16 + ((l >> 5) << 3) + i;
    int q = k >> 6, kk = k & 63;
    const float* Ws = (q & 1) ? sWr : sWl;
    Wfrag[id] = f2h(Ws[((2 * g + (q >> 1)) * 64 + kk) * 64 + d]);
  } else if (id < 65792) {                           // biasv[mt*32 + m32]
    int c = id - 65536;
    int mt = c >> 5, m32 = c & 31;
    int g = m32 & 3, tq = m32 >> 2;
    int d = mt * 8 + (tq >> 1) + 4 * (tq & 1);
    biasv[c] = sbl[(2 * g) * 64 + d] + sbl[(2 * g + 1) * 64 + d] + gb[g * 64 + d];
  } else {                                           // Bdec [nt][96 t][lane][8]
    int p = id - 65792;                              // < 147456
    int i = p & 7, l = (p >> 3) & 63;
    int rem = p >> 9;                                // nt*96 + t
    int nt = rem / 96, t = rem - nt * 96;
    int e = nt * 32 + (l & 31);
    int k = t * 16 + ((l >> 5) << 3) + i;
    Bdec[p] = (e < 72) ? f2h(dW[k * 72 + e]) : (unsigned short)0;
  }
}

// ---------------------------------------------------------------------------
// mono: all 24 cells for TWO batch elements per block.  32 KB LDS, 2 blk/CU.
// ---------------------------------------------------------------------------
__global__ __launch_bounds__(512, 4) void mono10_kernel(
    const float* __restrict__ src, const float* __restrict__ tgt,
    const float* __restrict__ encW, const float* __restrict__ encb,
    const float* __restrict__ gw,
    const unsigned short* __restrict__ Wfrag,
    const float* __restrict__ biasv,
    unsigned short* __restrict__ obuf)
{
  // frag layout: addr (u16) = (slot*64 + row + khalf*32)*8 + i, row<24, pad..31
  __shared__ __align__(16) unsigned short AGG[2][8 * 64 * 8];  // 16 KB [elem]
  __shared__ __align__(16) unsigned short XH[2][8 * 64 * 8];   // 16 KB [elem]

  const int tid = threadIdx.x;
  const int n2 = blockIdx.x * 2;
  const int w = tid >> 6, l = tid & 63;      // wave = M-tile mt = chunk owner
  const int l31 = l & 31, hi = l >> 5;

  // ---- persistent W: 1 M-tile x 16 k-steps = 64 VGPR ---------------------
  f16x8 W[16];
  {
    const f16x8* p0 = reinterpret_cast<const f16x8*>(Wfrag) + (w * 16) * 64 + l;
    #pragma unroll
    for (int t = 0; t < 16; ++t) W[t] = p0[t * 64];
  }
  // ---- bias (fp16-packed per acc-reg pair), gate_w scalars ---------------
  unsigned bias_u[8];
  #pragma unroll
  for (int p = 0; p < 8; ++p) {
    int r0 = 2 * p, r1 = 2 * p + 1;
    int m0 = (r0 & 3) + 8 * (r0 >> 2) + 4 * hi;
    int m1 = (r1 & 3) + 8 * (r1 >> 2) + 4 * hi;
    bias_u[p] = pk2h(biasv[w * 32 + m0], biasv[w * 32 + m1]);
  }
  float gwv[12];                             // d = w*8 + 4*hi + u
  #pragma unroll
  for (int g = 0; g < 3; ++g)
    #pragma unroll
    for (int u = 0; u < 4; ++u)
      gwv[g * 4 + u] = gw[g * 64 + w * 8 + 4 * hi + u];

  float creg[8];                             // c-state: [e][u]
  #pragma unroll
  for (int i = 0; i < 8; ++i) creg[i] = 0.0f;

  // ---- zero init XH (h = 0, pad rows incl. sentinel 24) ------------------
  {
    uint4 z = make_uint4(0, 0, 0, 0);
    uint4* xz = reinterpret_cast<uint4*>(&XH[0][0]);
    xz[tid] = z; xz[tid + 512] = z;          // 1024 uint4 = 16 KB
  }

  // encoder -> x-sections (slots 0-3) of XH[e]
  auto enc_to_x = [&](const float* f0, const float* f1) {
    #pragma unroll
    for (int ii = 0; ii < 6; ++ii) {
      int idx = tid + ii * 512;               // < 3072
      int e = (idx >= 1536) ? 1 : 0;
      int r = idx - e * 1536;
      int j = r >> 6, d = r & 63;
      const float* f = (e ? f1 : f0) + j * 3;
      float v = encb[d] + f[0] * encW[d] + f[1] * encW[64 + d] + f[2] * encW[128 + d];
      XH[e][((d >> 4) * 64 + j + ((d >> 3) & 1) * 32) * 8 + (d & 7)] =
          f2h(fmaxf(v, 0.0f));
    }
  };

  // wave-owned aggregation: wave w does chunk w (both sections), rows = l31
  auto agg_w = [&](int e) {
    if (l31 < 24) {
      const int sec = hi;
      const int Mrow = l31;
      const int sbase = (sec * 4 + (w >> 1)) * 64 + ((w & 1) << 5);
      const unsigned short* xh = &XH[e][0];
      f16x8 s = *reinterpret_cast<const f16x8*>(xh + (sbase + c_nbr2[Mrow][0]) * 8);
      #pragma unroll
      for (int m = 1; m < 5; ++m)             // sentinel 24 = zero pad row
        s += *reinterpret_cast<const f16x8*>(xh + (sbase + c_nbr2[Mrow][m]) * 8);
      s *= (_Float16)c_invdeg[Mrow];
      *reinterpret_cast<f16x8*>(&AGG[e][0] + (sbase + Mrow) * 8) = s;
    }
  };

  // GEMM: 16 MFMA, acc returned (AGPRs)
  auto gemm = [&](int e) -> f32x16 {
    const unsigned short* ab = &AGG[e][0];
    const unsigned short* xb = &XH[e][0];
    f32x16 acc;
    #pragma unroll
    for (int p = 0; p < 8; ++p) {
      acc[2 * p]     = h2f_lo(bias_u[p]);
      acc[2 * p + 1] = h2f_hi(bias_u[p]);
    }
    #pragma unroll
    for (int t = 0; t < 4; ++t)               // k 0..63: agg(x)
      acc = __builtin_amdgcn_mfma_f32_32x32x16_f16(
          W[t], *reinterpret_cast<const f16x8*>(ab + (t * 64 + l) * 8), acc, 0, 0, 0);
    #pragma unroll
    for (int t = 0; t < 4; ++t)               // k 64..127: x
      acc = __builtin_amdgcn_mfma_f32_32x32x16_f16(
          W[4 + t], *reinterpret_cast<const f16x8*>(xb + (t * 64 + l) * 8), acc, 0, 0, 0);
    #pragma unroll
    for (int t = 0; t < 4; ++t)               // k 128..191: agg(h)
      acc = __builtin_amdgcn_mfma_f32_32x32x16_f16(
          W[8 + t], *reinterpret_cast<const f16x8*>(ab + ((4 + t) * 64 + l) * 8), acc, 0, 0, 0);
    #pragma unroll
    for (int t = 0; t < 4; ++t)               // k 192..255: h
      acc = __builtin_amdgcn_mfma_f32_32x32x16_f16(
          W[12 + t], *reinterpret_cast<const f16x8*>(xb + ((4 + t) * 64 + l) * 8), acc, 0, 0, 0);
    return acc;
  };

  // epilogue: rows l31<24, d = w*8 + 4*hi + u (contiguous u) -> b64 writes
  auto epi = [&](const f32x16& acc, int e, int step, bool write_x) {
    if (l31 < 24) {
      float Ov[4], Hv[4];
      #pragma unroll
      for (int u = 0; u < 4; ++u) {
        float cv = creg[e * 4 + u];
        float I = sigm_(acc[4 * u + 0] + gwv[u] * cv);
        float F = sigm_(acc[4 * u + 1] + gwv[4 + u] * cv);
        float T = tanh_(acc[4 * u + 2]);
        float cn = F * cv + I * T;
        float O = sigm_(acc[4 * u + 3] + gwv[8 + u] * cn);
        Ov[u] = O;
        Hv[u] = O * tanh_(cn);
        creg[e * 4 + u] = cn;
      }
      uint2 ou, hu;
      ou.x = pkrtz(Ov[0], Ov[1]); ou.y = pkrtz(Ov[2], Ov[3]);
      hu.x = pkrtz(Hv[0], Hv[1]); hu.y = pkrtz(Hv[2], Hv[3]);
      unsigned short* xh = &XH[e][0];
      const int base = (((w >> 1) * 64 + l31 + ((w & 1) << 5)) << 3) + 4 * hi;
      if (write_x) *reinterpret_cast<uint2*>(xh + base) = ou;         // x slot
      *reinterpret_cast<uint2*>(xh + 2048 + base) = hu;               // h slot
      if (step >= 12)
        *reinterpret_cast<uint2*>(
            obuf + (size_t)((n2 + e) * 12 + step - 12) * 1536 + l31 * 64 + w * 8 + 4 * hi) = ou;
    }
  };

  // ---- prologue ----------------------------------------------------------
  __syncthreads();                            // XH zero visible
  enc_to_x(src + ((size_t)n2 * 16 + 4) * 72,
           src + ((size_t)(n2 + 1) * 16 + 4) * 72);
  __syncthreads();
  agg_w(0);
  __syncthreads();

  f32x16 acc0, acc1;
  #pragma unroll 1
  for (int step = 0; step < 24; ++step) {
    if (step == 12) {                         // decode init: re-encode tgt[:,0]
      enc_to_x(tgt + (size_t)n2 * 864, tgt + (size_t)(n2 + 1) * 864);
      __syncthreads();
      agg_w(0);                               // redo agg(e0,12) with fresh x
      __syncthreads();
    }
    // P1: MFMA(e0,s) || epi(e1,s-1) -> agg(e1,s)   (independent streams)
    acc0 = gemm(0);
    if (step > 0) epi(acc1, 1, step - 1, step != 12);
    agg_w(1);
    __syncthreads();
    // P2: MFMA(e1,s) || epi(e0,s) -> agg(e0,s+1)
    acc1 = gemm(1);
    epi(acc0, 0, step, true);
    if (step < 23) agg_w(0);
    __syncthreads();
  }
  epi(acc1, 1, 23, false);                    // final e1 epilogue (obuf only)
}

// ---------------------------------------------------------------------------
// dec: out[row][e] = O[row,:] . decW[:,e] + db[e]; rows = n*12+ts.
// block: 32 rows, 4 waves K-split (384 each), 3 col-tiles, LDS reduce.
// ---------------------------------------------------------------------------
__global__ __launch_bounds__(256) void dec4_kernel(
    const unsigned short* __restrict__ obuf,
    const unsigned short* __restrict__ Bdec,
    const float* __restrict__ db,
    float* __restrict__ out)
{
  __shared__ float part[4 * 3 * 64 * 16];    // 48 KB
  const int tid = threadIdx.x;
  const int w = tid >> 6, l = tid & 63;
  const int l31 = l & 31, hi = l >> 5;
  const int r0 = blockIdx.x * 32;

  f32x16 a0, a1, a2;
  #pragma unroll
  for (int r = 0; r < 16; ++r) { a0[r] = 0.f; a1[r] = 0.f; a2[r] = 0.f; }

  const unsigned short* Ap = obuf + (size_t)(r0 + l31) * 1536 + hi * 8;
  #pragma unroll 4
  for (int tt = 0; tt < 24; ++tt) {
    int kt = w * 24 + tt;
    f16x8 av = *reinterpret_cast<const f16x8*>(Ap + kt * 16);
    f16x8 b0 = *reinterpret_cast<const f16x8*>(Bdec + ((0 * 96 + kt) * 64 + l) * 8);
    f16x8 b1 = *reinterpret_cast<const f16x8*>(Bdec + ((1 * 96 + kt) * 64 + l) * 8);
    f16x8 b2 = *reinterpret_cast<const f16x8*>(Bdec + ((2 * 96 + kt) * 64 + l) * 8);
    a0 = __builtin_amdgcn_mfma_f32_32x32x16_f16(av, b0, a0, 0, 0, 0);
    a1 = __builtin_amdgcn_mfma_f32_32x32x16_f16(av, b1, a1, 0, 0, 0);
    a2 = __builtin_amdgcn_mfma_f32_32x32x16_f16(av, b2, a2, 0, 0, 0);
  }
  #pragma unroll
  for (int r = 0; r < 16; ++r) {
    part[((w * 3 + 0) * 64 + l) * 16 + r] = a0[r];
    part[((w * 3 + 1) * 64 + l) * 16 + r] = a1[r];
    part[((w * 3 + 2) * 64 + l) * 16 + r] = a2[r];
  }
  __syncthreads();

  // reduce 4 K-partials; thread -> (row = tid>>3, e = (tid&7)*12 + 0..11)
  int row = tid >> 3;
  int hi2 = (row >> 2) & 1;
  int rr = 4 * (row >> 3) + (row & 3);
  #pragma unroll
  for (int ei = 0; ei < 12; ++ei) {
    int e = (tid & 7) * 12 + ei;
    if (e < 72) {
      int nt = e >> 5, e32 = e & 31;
      float s = db[e];
      #pragma unroll
      for (int w2 = 0; w2 < 4; ++w2)
        s += part[((w2 * 3 + nt) * 64 + e32 + 32 * hi2) * 16 + rr];
      out[(size_t)(r0 + row) * 72 + e] = s;
    }
  }
}

// ---------------------------------------------------------------------------
extern "C" void kernel_launch(void* const* d_in, const int* in_sizes, int n_in,
                              void* d_out, int out_size, void* d_ws, size_t ws_size,
                              hipStream_t stream) {
  const float* src  = (const float*)d_in[0];   // [1024,16,72]
  const float* tgt  = (const float*)d_in[1];   // [1024,12,72]
  const float* encW = (const float*)d_in[2];   // [3,64]
  const float* encb = (const float*)d_in[3];   // [64]
  const float* sWl  = (const float*)d_in[4];   // [8,64,64]
  const float* sbl  = (const float*)d_in[5];   // [8,64]
  const float* sWr  = (const float*)d_in[6];   // [8,64,64]
  const float* gw   = (const float*)d_in[7];   // [3,1,64]
  const float* gb   = (const float*)d_in[8];   // [4,1,64]
  const float* dW   = (const float*)d_in[9];   // [1536,72]
  const float* db   = (const float*)d_in[10];  // [72]
  float* out = (float*)d_out;

  unsigned short* obuf  = (unsigned short*)d_ws;        // 12288*1536 fp16
  unsigned short* Wfrag = obuf + (size_t)12288 * 1536;  // 65536 fp16
  unsigned short* Bdec  = Wfrag + 65536;                // 147456 fp16
  float*          biasv = (float*)(Bdec + 147456);      // 256 f32

  prep5_kernel<<<833, 256, 0, stream>>>(sWl, sbl, sWr, gb, dW, Wfrag, biasv, Bdec);
  mono10_kernel<<<512, 512, 0, stream>>>(src, tgt, encW, encb, gw, Wfrag, biasv, obuf);
  dec4_kernel<<<384, 256, 0, stream>>>(obuf, Bdec, db, out);
}

// Round 11
// 190.509 us; speedup vs baseline: 1.3185x; 1.3185x over previous
//
#include <hip/hip_runtime.h>

// ---------------------------------------------------------------------------
// SAGE-GCN LSTM, N=1024, J=24, D=64.  R11 = R9 schedule + R10 micro-wins:
//  mono: 512 blocks (2/CU) x 512 thr (8 waves), 2 elems/block, 24 cells.
//   Phase-local accumulator (NO cross-barrier acc - R10's 2-acc deferral
//   spilled ~8B/thread/step to scratch: FETCH 70MB, +42us). XH double-buf.
//   P1: gemm(e0,cur) || agg(e1,cur)      -> epi(e0) writes XH[cur^1]
//   P2: gemm(e1,cur) || agg(e0,cur^1!)   -> epi(e1) writes XH[cur^1]
//   Kept from R10: M-remap (d7 = u + 4*hi -> b64 epi/obuf writes),
//   wave-chunk-owned agg (balanced, conflict-light), fp16 state/W/pk-adds.
//  dec: fp16 MFMA, 4-wave K-split + LDS reduce.  prep: weight packing.
// ---------------------------------------------------------------------------

typedef _Float16 f16x8 __attribute__((ext_vector_type(8)));
typedef float f32x16 __attribute__((ext_vector_type(16)));

// neighbor table with sentinel 24 (zero pad row) instead of -1: always 5 reads
__constant__ int c_nbr2[24][5] = {
  {0,1,2,3,24},  {1,0,4,24,24}, {2,0,5,24,24}, {3,0,6,24,24},
  {4,1,7,24,24}, {5,2,8,24,24}, {6,3,9,24,24}, {7,4,10,24,24},
  {8,5,11,24,24},{9,6,12,13,14},{10,7,24,24,24},{11,8,24,24,24},
  {12,9,15,24,24},{13,9,16,24,24},{14,9,17,24,24},{15,12,24,24,24},
  {16,13,18,24,24},{17,14,19,24,24},{18,16,20,24,24},{19,17,21,24,24},
  {20,18,22,24,24},{21,19,23,24,24},{22,20,24,24,24},{23,21,24,24,24}
};
__constant__ float c_invdeg[24] = {
  0.25f, 1.f/3.f, 1.f/3.f, 1.f/3.f, 1.f/3.f, 1.f/3.f, 1.f/3.f, 1.f/3.f,
  1.f/3.f, 0.2f, 0.5f, 0.5f, 1.f/3.f, 1.f/3.f, 1.f/3.f, 0.5f,
  1.f/3.f, 1.f/3.f, 1.f/3.f, 1.f/3.f, 1.f/3.f, 1.f/3.f, 0.5f, 0.5f
};

__device__ __forceinline__ unsigned short f2h(float f) {
  _Float16 h = (_Float16)f;
  return __builtin_bit_cast(unsigned short, h);
}
__device__ __forceinline__ unsigned pk2h(float a, float b) {
  return (unsigned)f2h(a) | ((unsigned)f2h(b) << 16);
}
__device__ __forceinline__ unsigned pkrtz(float lo, float hi) {  // 1 inst
  unsigned r;
  asm("v_cvt_pkrtz_f16_f32 %0, %1, %2" : "=v"(r) : "v"(lo), "v"(hi));
  return r;
}
__device__ __forceinline__ float h2f_lo(unsigned u) {
  return (float)__builtin_bit_cast(_Float16, (unsigned short)(u & 0xffff));
}
__device__ __forceinline__ float h2f_hi(unsigned u) {
  return (float)__builtin_bit_cast(_Float16, (unsigned short)(u >> 16));
}
__device__ __forceinline__ float sigm_(float x) {
  return __builtin_amdgcn_rcpf(1.0f + __expf(-x));
}
__device__ __forceinline__ float tanh_(float x) {
  return 1.0f - 2.0f * __builtin_amdgcn_rcpf(1.0f + __expf(2.0f * x));
}

// ---------------------------------------------------------------------------
// prep: Wfrag (fp16, A-frag layout), biasv f32, Bdec fp16.
//  m32 -> (g, d): g = m32 & 3; tq = m32>>2; d = mt*8 + (tq>>1) + 4*(tq&1).
//  (acc reg r, lane-hi -> gate r&3 at d7 = (r>>2)+4*hi: thread's 4 u-values
//   are CONTIGUOUS in d -> b64 epilogue writes.)
//  k = t*16 + (lane>>5)*8 + i; q=k>>6: q0 Wl[2g], q1 Wr[2g], q2 Wl[2g+1], q3 Wr[2g+1]
// ---------------------------------------------------------------------------
__global__ void prep5_kernel(const float* __restrict__ sWl, const float* __restrict__ sbl,
                             const float* __restrict__ sWr, const float* __restrict__ gb,
                             const float* __restrict__ dW,
                             unsigned short* __restrict__ Wfrag,
                             float* __restrict__ biasv,
                             unsigned short* __restrict__ Bdec)
{
  int id = blockIdx.x * 256 + threadIdx.x;          // 213248 total
  if (id < 65536) {                                  // Wfrag [mt][t][lane][8]
    int i = id & 7, l = (id >> 3) & 63, t = (id >> 9) & 15, mt = id >> 13;
    int m32 = l & 31;
    int g = m32 & 3, tq = m32 >> 2;
    int d = mt * 8 + (tq >> 1) + 4 * (tq & 1);
    int k = t * 16 + ((l >> 5) << 3) + i;
    int q = k >> 6, kk = k & 63;
    const float* Ws = (q & 1) ? sWr : sWl;
    Wfrag[id] = f2h(Ws[((2 * g + (q >> 1)) * 64 + kk) * 64 + d]);
  } else if (id < 65792) {                           // biasv[mt*32 + m32]
    int c = id - 65536;
    int mt = c >> 5, m32 = c & 31;
    int g = m32 & 3, tq = m32 >> 2;
    int d = mt * 8 + (tq >> 1) + 4 * (tq & 1);
    biasv[c] = sbl[(2 * g) * 64 + d] + sbl[(2 * g + 1) * 64 + d] + gb[g * 64 + d];
  } else {                                           // Bdec [nt][96 t][lane][8]
    int p = id - 65792;                              // < 147456
    int i = p & 7, l = (p >> 3) & 63;
    int rem = p >> 9;                                // nt*96 + t
    int nt = rem / 96, t = rem - nt * 96;
    int e = nt * 32 + (l & 31);
    int k = t * 16 + ((l >> 5) << 3) + i;
    Bdec[p] = (e < 72) ? f2h(dW[k * 72 + e]) : (unsigned short)0;
  }
}

// ---------------------------------------------------------------------------
// mono: all 24 cells for TWO batch elements per block.  48 KB LDS, 2 blk/CU.
// ---------------------------------------------------------------------------
__global__ __launch_bounds__(512, 4) void mono11_kernel(
    const float* __restrict__ src, const float* __restrict__ tgt,
    const float* __restrict__ encW, const float* __restrict__ encb,
    const float* __restrict__ gw,
    const unsigned short* __restrict__ Wfrag,
    const float* __restrict__ biasv,
    unsigned short* __restrict__ obuf)
{
  // frag layout: addr (u16) = (slot*64 + row + khalf*32)*8 + i, row<24, pad..31
  __shared__ __align__(16) unsigned short AGG[2][8 * 64 * 8];     // 16 KB [elem]
  __shared__ __align__(16) unsigned short XH[2][2][8 * 64 * 8];   // 32 KB [buf][elem]

  const int tid = threadIdx.x;
  const int n2 = blockIdx.x * 2;
  const int w = tid >> 6, l = tid & 63;      // wave = M-tile mt = chunk owner
  const int l31 = l & 31, hi = l >> 5;

  // ---- persistent W: 1 M-tile x 16 k-steps = 64 VGPR ---------------------
  f16x8 W[16];
  {
    const f16x8* p0 = reinterpret_cast<const f16x8*>(Wfrag) + (w * 16) * 64 + l;
    #pragma unroll
    for (int t = 0; t < 16; ++t) W[t] = p0[t * 64];
  }
  // ---- bias (fp16-packed per acc-reg pair), gate_w scalars ---------------
  unsigned bias_u[8];
  #pragma unroll
  for (int p = 0; p < 8; ++p) {
    int r0 = 2 * p, r1 = 2 * p + 1;
    int m0 = (r0 & 3) + 8 * (r0 >> 2) + 4 * hi;
    int m1 = (r1 & 3) + 8 * (r1 >> 2) + 4 * hi;
    bias_u[p] = pk2h(biasv[w * 32 + m0], biasv[w * 32 + m1]);
  }
  float gwv[12];                             // d = w*8 + 4*hi + u
  #pragma unroll
  for (int g = 0; g < 3; ++g)
    #pragma unroll
    for (int u = 0; u < 4; ++u)
      gwv[g * 4 + u] = gw[g * 64 + w * 8 + 4 * hi + u];

  float creg[8];                             // c-state: [e][u]
  #pragma unroll
  for (int i = 0; i < 8; ++i) creg[i] = 0.0f;

  // ---- zero init XH (both bufs) + AGG (pads & h=0) ------------------------
  {
    uint4 z = make_uint4(0, 0, 0, 0);
    uint4* xz = reinterpret_cast<uint4*>(&XH[0][0][0]);
    #pragma unroll
    for (int i = 0; i < 4; ++i) xz[tid + i * 512] = z;   // 2048 uint4 = 32 KB
    uint4* az = reinterpret_cast<uint4*>(&AGG[0][0]);
    #pragma unroll
    for (int i = 0; i < 2; ++i) az[tid + i * 512] = z;   // 1024 uint4 = 16 KB
  }

  // encoder -> x-sections (slots 0-3) of XH[buf][e]
  auto enc_to_x = [&](const float* f0, const float* f1, int buf) {
    #pragma unroll
    for (int ii = 0; ii < 6; ++ii) {
      int idx = tid + ii * 512;               // < 3072
      int e = (idx >= 1536) ? 1 : 0;
      int r = idx - e * 1536;
      int j = r >> 6, d = r & 63;
      const float* f = (e ? f1 : f0) + j * 3;
      float v = encb[d] + f[0] * encW[d] + f[1] * encW[64 + d] + f[2] * encW[128 + d];
      XH[buf][e][((d >> 4) * 64 + j + ((d >> 3) & 1) * 32) * 8 + (d & 7)] =
          f2h(fmaxf(v, 0.0f));
    }
  };

  // wave-owned aggregation: wave w does chunk w, sec = hi, rows = l31
  auto agg_w = [&](int e, int buf) {
    if (l31 < 24) {
      const int sec = hi;
      const int Mrow = l31;
      const int sbase = (sec * 4 + (w >> 1)) * 64 + ((w & 1) << 5);
      const unsigned short* xh = &XH[buf][e][0];
      f16x8 s = *reinterpret_cast<const f16x8*>(xh + (sbase + c_nbr2[Mrow][0]) * 8);
      #pragma unroll
      for (int m = 1; m < 5; ++m)             // sentinel 24 = zero pad row
        s += *reinterpret_cast<const f16x8*>(xh + (sbase + c_nbr2[Mrow][m]) * 8);
      s *= (_Float16)c_invdeg[Mrow];
      *reinterpret_cast<f16x8*>(&AGG[e][0] + (sbase + Mrow) * 8) = s;
    }
  };

  // GEMM: 16 MFMA, phase-local acc
  auto gemm = [&](int e, int buf) -> f32x16 {
    const unsigned short* ab = &AGG[e][0];
    const unsigned short* xb = &XH[buf][e][0];
    f32x16 acc;
    #pragma unroll
    for (int p = 0; p < 8; ++p) {
      acc[2 * p]     = h2f_lo(bias_u[p]);
      acc[2 * p + 1] = h2f_hi(bias_u[p]);
    }
    #pragma unroll
    for (int t = 0; t < 4; ++t)               // k 0..63: agg(x)
      acc = __builtin_amdgcn_mfma_f32_32x32x16_f16(
          W[t], *reinterpret_cast<const f16x8*>(ab + (t * 64 + l) * 8), acc, 0, 0, 0);
    #pragma unroll
    for (int t = 0; t < 4; ++t)               // k 64..127: x
      acc = __builtin_amdgcn_mfma_f32_32x32x16_f16(
          W[4 + t], *reinterpret_cast<const f16x8*>(xb + (t * 64 + l) * 8), acc, 0, 0, 0);
    #pragma unroll
    for (int t = 0; t < 4; ++t)               // k 128..191: agg(h)
      acc = __builtin_amdgcn_mfma_f32_32x32x16_f16(
          W[8 + t], *reinterpret_cast<const f16x8*>(ab + ((4 + t) * 64 + l) * 8), acc, 0, 0, 0);
    #pragma unroll
    for (int t = 0; t < 4; ++t)               // k 192..255: h
      acc = __builtin_amdgcn_mfma_f32_32x32x16_f16(
          W[12 + t], *reinterpret_cast<const f16x8*>(xb + ((4 + t) * 64 + l) * 8), acc, 0, 0, 0);
    return acc;
  };

  // epilogue: rows l31<24, d = w*8 + 4*hi + u (contiguous) -> b64 writes
  auto epi = [&](const f32x16& acc, int e, int step, int wbuf) {
    if (l31 < 24) {
      float Ov[4], Hv[4];
      #pragma unroll
      for (int u = 0; u < 4; ++u) {
        float cv = creg[e * 4 + u];
        float I = sigm_(acc[4 * u + 0] + gwv[u] * cv);
        float F = sigm_(acc[4 * u + 1] + gwv[4 + u] * cv);
        float T = tanh_(acc[4 * u + 2]);
        float cn = F * cv + I * T;
        float O = sigm_(acc[4 * u + 3] + gwv[8 + u] * cn);
        Ov[u] = O;
        Hv[u] = O * tanh_(cn);
        creg[e * 4 + u] = cn;
      }
      uint2 ou, hu;
      ou.x = pkrtz(Ov[0], Ov[1]); ou.y = pkrtz(Ov[2], Ov[3]);
      hu.x = pkrtz(Hv[0], Hv[1]); hu.y = pkrtz(Hv[2], Hv[3]);
      unsigned short* xh = &XH[wbuf][e][0];
      const int base = (((w >> 1) * 64 + l31 + ((w & 1) << 5)) << 3) + 4 * hi;
      *reinterpret_cast<uint2*>(xh + base) = ou;          // x slot
      *reinterpret_cast<uint2*>(xh + 2048 + base) = hu;   // h slot
      if (step >= 12)
        *reinterpret_cast<uint2*>(
            obuf + (size_t)((n2 + e) * 12 + step - 12) * 1536 + l31 * 64 + w * 8 + 4 * hi) = ou;
    }
  };

  // ---- prologue ----------------------------------------------------------
  __syncthreads();                            // zero-init visible
  enc_to_x(src + ((size_t)n2 * 16 + 4) * 72,
           src + ((size_t)(n2 + 1) * 16 + 4) * 72, 0);
  __syncthreads();
  agg_w(0, 0);
  __syncthreads();

  int cur = 0;
  #pragma unroll 1
  for (int step = 0; step < 24; ++step) {
    if (step == 12) {                         // decode init: re-encode tgt[:,0]
      enc_to_x(tgt + (size_t)n2 * 864, tgt + (size_t)(n2 + 1) * 864, cur);
      __syncthreads();
      agg_w(0, cur);                          // AGG[0] from fresh x
      __syncthreads();
    }
    // P1: gemm(e0) || agg(e1, this step) ; epi(e0) -> XH[cur^1]
    {
      f32x16 acc = gemm(0, cur);
      agg_w(1, cur);
      epi(acc, 0, step, cur ^ 1);
    }
    __syncthreads();
    // P2: gemm(e1) || agg(e0, NEXT step from fresh XH[cur^1]) ; epi(e1)
    {
      f32x16 acc = gemm(1, cur);
      if (step < 23) agg_w(0, cur ^ 1);
      epi(acc, 1, step, cur ^ 1);
    }
    __syncthreads();
    cur ^= 1;
  }
}

// ---------------------------------------------------------------------------
// dec: out[row][e] = O[row,:] . decW[:,e] + db[e]; rows = n*12+ts.
// block: 32 rows, 4 waves K-split (384 each), 3 col-tiles, LDS reduce.
// ---------------------------------------------------------------------------
__global__ __launch_bounds__(256) void dec4_kernel(
    const unsigned short* __restrict__ obuf,
    const unsigned short* __restrict__ Bdec,
    const float* __restrict__ db,
    float* __restrict__ out)
{
  __shared__ float part[4 * 3 * 64 * 16];    // 48 KB
  const int tid = threadIdx.x;
  const int w = tid >> 6, l = tid & 63;
  const int l31 = l & 31, hi = l >> 5;
  const int r0 = blockIdx.x * 32;

  f32x16 a0, a1, a2;
  #pragma unroll
  for (int r = 0; r < 16; ++r) { a0[r] = 0.f; a1[r] = 0.f; a2[r] = 0.f; }

  const unsigned short* Ap = obuf + (size_t)(r0 + l31) * 1536 + hi * 8;
  #pragma unroll 4
  for (int tt = 0; tt < 24; ++tt) {
    int kt = w * 24 + tt;
    f16x8 av = *reinterpret_cast<const f16x8*>(Ap + kt * 16);
    f16x8 b0 = *reinterpret_cast<const f16x8*>(Bdec + ((0 * 96 + kt) * 64 + l) * 8);
    f16x8 b1 = *reinterpret_cast<const f16x8*>(Bdec + ((1 * 96 + kt) * 64 + l) * 8);
    f16x8 b2 = *reinterpret_cast<const f16x8*>(Bdec + ((2 * 96 + kt) * 64 + l) * 8);
    a0 = __builtin_amdgcn_mfma_f32_32x32x16_f16(av, b0, a0, 0, 0, 0);
    a1 = __builtin_amdgcn_mfma_f32_32x32x16_f16(av, b1, a1, 0, 0, 0);
    a2 = __builtin_amdgcn_mfma_f32_32x32x16_f16(av, b2, a2, 0, 0, 0);
  }
  #pragma unroll
  for (int r = 0; r < 16; ++r) {
    part[((w * 3 + 0) * 64 + l) * 16 + r] = a0[r];
    part[((w * 3 + 1) * 64 + l) * 16 + r] = a1[r];
    part[((w * 3 + 2) * 64 + l) * 16 + r] = a2[r];
  }
  __syncthreads();

  // reduce 4 K-partials; thread -> (row = tid>>3, e = (tid&7)*12 + 0..11)
  int row = tid >> 3;
  int hi2 = (row >> 2) & 1;
  int rr = 4 * (row >> 3) + (row & 3);
  #pragma unroll
  for (int ei = 0; ei < 12; ++ei) {
    int e = (tid & 7) * 12 + ei;
    if (e < 72) {
      int nt = e >> 5, e32 = e & 31;
      float s = db[e];
      #pragma unroll
      for (int w2 = 0; w2 < 4; ++w2)
        s += part[((w2 * 3 + nt) * 64 + e32 + 32 * hi2) * 16 + rr];
      out[(size_t)(r0 + row) * 72 + e] = s;
    }
  }
}

// ---------------------------------------------------------------------------
extern "C" void kernel_launch(void* const* d_in, const int* in_sizes, int n_in,
                              void* d_out, int out_size, void* d_ws, size_t ws_size,
                              hipStream_t stream) {
  const float* src  = (const float*)d_in[0];   // [1024,16,72]
  const float* tgt  = (const float*)d_in[1];   // [1024,12,72]
  const float* encW = (const float*)d_in[2];   // [3,64]
  const float* encb = (const float*)d_in[3];   // [64]
  const float* sWl  = (const float*)d_in[4];   // [8,64,64]
  const float* sbl  = (const float*)d_in[5];   // [8,64]
  const float* sWr  = (const float*)d_in[6];   // [8,64,64]
  const float* gw   = (const float*)d_in[7];   // [3,1,64]
  const float* gb   = (const float*)d_in[8];   // [4,1,64]
  const float* dW   = (const float*)d_in[9];   // [1536,72]
  const float* db   = (const float*)d_in[10];  // [72]
  float* out = (float*)d_out;

  unsigned short* obuf  = (unsigned short*)d_ws;        // 12288*1536 fp16
  unsigned short* Wfrag = obuf + (size_t)12288 * 1536;  // 65536 fp16
  unsigned short* Bdec  = Wfrag + 65536;                // 147456 fp16
  float*          biasv = (float*)(Bdec + 147456);      // 256 f32

  prep5_kernel<<<833, 256, 0, stream>>>(sWl, sbl, sWr, gb, dW, Wfrag, biasv, Bdec);
  mono11_kernel<<<512, 512, 0, stream>>>(src, tgt, encW, encb, gw, Wfrag, biasv, obuf);
  dec4_kernel<<<384, 256, 0, stream>>>(obuf, Bdec, db, out);
}

// Round 12
// 182.122 us; speedup vs baseline: 1.3792x; 1.0460x over previous
//
#include <hip/hip_runtime.h>

// ---------------------------------------------------------------------------
// SAGE-GCN LSTM, N=1024, J=24, D=64.  R12 = single-barrier steps + setprio:
//  mono: 512 blocks (2/CU) x 512 thr (8 waves), 2 elems/block, 24 cells.
//   ONE barrier per step: per wave sequentially
//     {gemm(e0,cur) -> epi(e0 -> XH[nxt]) -> agg(e0, XH[nxt] -> AGG[nxt])}
//     {gemm(e1,cur) -> epi(e1 -> XH[nxt]) -> agg(e1, XH[nxt] -> AGG[nxt])}
//   Mid-step barrier removable because agg(chunk w) reads ONLY chunk w rows,
//   written by wave w's own epi (same-wave LDS ordering). AGG double-buffered
//   (64 KB LDS total, still 2 blocks/CU). Waves de-lockstep within a step ->
//   VALU/LDS/MFMA overlap across waves. s_setprio(1) wraps MFMA chains (T5).
//   Phase-local single acc (no cross-barrier acc -> no R10-style spill).
//  dec: fp16 MFMA, 4-wave K-split + LDS reduce.  prep: weight packing.
// ---------------------------------------------------------------------------

typedef _Float16 f16x8 __attribute__((ext_vector_type(8)));
typedef float f32x16 __attribute__((ext_vector_type(16)));

// neighbor table with sentinel 24 (zero pad row) instead of -1: always 5 reads
__constant__ int c_nbr2[24][5] = {
  {0,1,2,3,24},  {1,0,4,24,24}, {2,0,5,24,24}, {3,0,6,24,24},
  {4,1,7,24,24}, {5,2,8,24,24}, {6,3,9,24,24}, {7,4,10,24,24},
  {8,5,11,24,24},{9,6,12,13,14},{10,7,24,24,24},{11,8,24,24,24},
  {12,9,15,24,24},{13,9,16,24,24},{14,9,17,24,24},{15,12,24,24,24},
  {16,13,18,24,24},{17,14,19,24,24},{18,16,20,24,24},{19,17,21,24,24},
  {20,18,22,24,24},{21,19,23,24,24},{22,20,24,24,24},{23,21,24,24,24}
};
__constant__ float c_invdeg[24] = {
  0.25f, 1.f/3.f, 1.f/3.f, 1.f/3.f, 1.f/3.f, 1.f/3.f, 1.f/3.f, 1.f/3.f,
  1.f/3.f, 0.2f, 0.5f, 0.5f, 1.f/3.f, 1.f/3.f, 1.f/3.f, 0.5f,
  1.f/3.f, 1.f/3.f, 1.f/3.f, 1.f/3.f, 1.f/3.f, 1.f/3.f, 0.5f, 0.5f
};

__device__ __forceinline__ unsigned short f2h(float f) {
  _Float16 h = (_Float16)f;
  return __builtin_bit_cast(unsigned short, h);
}
__device__ __forceinline__ unsigned pk2h(float a, float b) {
  return (unsigned)f2h(a) | ((unsigned)f2h(b) << 16);
}
__device__ __forceinline__ unsigned pkrtz(float lo, float hi) {  // 1 inst
  unsigned r;
  asm("v_cvt_pkrtz_f16_f32 %0, %1, %2" : "=v"(r) : "v"(lo), "v"(hi));
  return r;
}
__device__ __forceinline__ float h2f_lo(unsigned u) {
  return (float)__builtin_bit_cast(_Float16, (unsigned short)(u & 0xffff));
}
__device__ __forceinline__ float h2f_hi(unsigned u) {
  return (float)__builtin_bit_cast(_Float16, (unsigned short)(u >> 16));
}
__device__ __forceinline__ float sigm_(float x) {
  return __builtin_amdgcn_rcpf(1.0f + __expf(-x));
}
__device__ __forceinline__ float tanh_(float x) {
  return 1.0f - 2.0f * __builtin_amdgcn_rcpf(1.0f + __expf(2.0f * x));
}

// ---------------------------------------------------------------------------
// prep: Wfrag (fp16, A-frag layout), biasv f32, Bdec fp16.
//  m32 -> (g, d): g = m32 & 3; tq = m32>>2; d = mt*8 + (tq>>1) + 4*(tq&1).
//  (acc reg r, lane-hi -> gate r&3 at d7 = (r>>2)+4*hi: thread's 4 u-values
//   are CONTIGUOUS in d -> b64 epilogue writes.)
//  k = t*16 + (lane>>5)*8 + i; q=k>>6: q0 Wl[2g], q1 Wr[2g], q2 Wl[2g+1], q3 Wr[2g+1]
// ---------------------------------------------------------------------------
__global__ void prep5_kernel(const float* __restrict__ sWl, const float* __restrict__ sbl,
                             const float* __restrict__ sWr, const float* __restrict__ gb,
                             const float* __restrict__ dW,
                             unsigned short* __restrict__ Wfrag,
                             float* __restrict__ biasv,
                             unsigned short* __restrict__ Bdec)
{
  int id = blockIdx.x * 256 + threadIdx.x;          // 213248 total
  if (id < 65536) {                                  // Wfrag [mt][t][lane][8]
    int i = id & 7, l = (id >> 3) & 63, t = (id >> 9) & 15, mt = id >> 13;
    int m32 = l & 31;
    int g = m32 & 3, tq = m32 >> 2;
    int d = mt * 8 + (tq >> 1) + 4 * (tq & 1);
    int k = t * 16 + ((l >> 5) << 3) + i;
    int q = k >> 6, kk = k & 63;
    const float* Ws = (q & 1) ? sWr : sWl;
    Wfrag[id] = f2h(Ws[((2 * g + (q >> 1)) * 64 + kk) * 64 + d]);
  } else if (id < 65792) {                           // biasv[mt*32 + m32]
    int c = id - 65536;
    int mt = c >> 5, m32 = c & 31;
    int g = m32 & 3, tq = m32 >> 2;
    int d = mt * 8 + (tq >> 1) + 4 * (tq & 1);
    biasv[c] = sbl[(2 * g) * 64 + d] + sbl[(2 * g + 1) * 64 + d] + gb[g * 64 + d];
  } else {                                           // Bdec [nt][96 t][lane][8]
    int p = id - 65792;                              // < 147456
    int i = p & 7, l = (p >> 3) & 63;
    int rem = p >> 9;                                // nt*96 + t
    int nt = rem / 96, t = rem - nt * 96;
    int e = nt * 32 + (l & 31);
    int k = t * 16 + ((l >> 5) << 3) + i;
    Bdec[p] = (e < 72) ? f2h(dW[k * 72 + e]) : (unsigned short)0;
  }
}

// ---------------------------------------------------------------------------
// mono: all 24 cells for TWO batch elements per block.  64 KB LDS, 2 blk/CU.
// ---------------------------------------------------------------------------
__global__ __launch_bounds__(512, 4) void mono12_kernel(
    const float* __restrict__ src, const float* __restrict__ tgt,
    const float* __restrict__ encW, const float* __restrict__ encb,
    const float* __restrict__ gw,
    const unsigned short* __restrict__ Wfrag,
    const float* __restrict__ biasv,
    unsigned short* __restrict__ obuf)
{
  // frag layout: addr (u16) = (slot*64 + row + khalf*32)*8 + i, row<24, pad..31
  __shared__ __align__(16) unsigned short AGG[2][2][8 * 64 * 8];  // 32 KB [buf][elem]
  __shared__ __align__(16) unsigned short XH[2][2][8 * 64 * 8];   // 32 KB [buf][elem]

  const int tid = threadIdx.x;
  const int n2 = blockIdx.x * 2;
  const int w = tid >> 6, l = tid & 63;      // wave = M-tile mt = chunk owner
  const int l31 = l & 31, hi = l >> 5;

  // ---- persistent W: 1 M-tile x 16 k-steps = 64 VGPR ---------------------
  f16x8 W[16];
  {
    const f16x8* p0 = reinterpret_cast<const f16x8*>(Wfrag) + (w * 16) * 64 + l;
    #pragma unroll
    for (int t = 0; t < 16; ++t) W[t] = p0[t * 64];
  }
  // ---- bias (fp16-packed per acc-reg pair), gate_w scalars ---------------
  unsigned bias_u[8];
  #pragma unroll
  for (int p = 0; p < 8; ++p) {
    int r0 = 2 * p, r1 = 2 * p + 1;
    int m0 = (r0 & 3) + 8 * (r0 >> 2) + 4 * hi;
    int m1 = (r1 & 3) + 8 * (r1 >> 2) + 4 * hi;
    bias_u[p] = pk2h(biasv[w * 32 + m0], biasv[w * 32 + m1]);
  }
  float gwv[12];                             // d = w*8 + 4*hi + u
  #pragma unroll
  for (int g = 0; g < 3; ++g)
    #pragma unroll
    for (int u = 0; u < 4; ++u)
      gwv[g * 4 + u] = gw[g * 64 + w * 8 + 4 * hi + u];

  float creg[8];                             // c-state: [e][u]
  #pragma unroll
  for (int i = 0; i < 8; ++i) creg[i] = 0.0f;

  // ---- zero init XH + AGG (both bufs: h=0, pad rows) ---------------------
  {
    uint4 z = make_uint4(0, 0, 0, 0);
    uint4* xz = reinterpret_cast<uint4*>(&XH[0][0][0]);
    #pragma unroll
    for (int i = 0; i < 4; ++i) xz[tid + i * 512] = z;   // 32 KB
    uint4* az = reinterpret_cast<uint4*>(&AGG[0][0][0]);
    #pragma unroll
    for (int i = 0; i < 4; ++i) az[tid + i * 512] = z;   // 32 KB
  }

  // encoder -> x-sections (slots 0-3) of XH[buf][e]
  auto enc_to_x = [&](const float* f0, const float* f1, int buf) {
    #pragma unroll
    for (int ii = 0; ii < 6; ++ii) {
      int idx = tid + ii * 512;               // < 3072
      int e = (idx >= 1536) ? 1 : 0;
      int r = idx - e * 1536;
      int j = r >> 6, d = r & 63;
      const float* f = (e ? f1 : f0) + j * 3;
      float v = encb[d] + f[0] * encW[d] + f[1] * encW[64 + d] + f[2] * encW[128 + d];
      XH[buf][e][((d >> 4) * 64 + j + ((d >> 3) & 1) * 32) * 8 + (d & 7)] =
          f2h(fmaxf(v, 0.0f));
    }
  };

  // wave-owned aggregation: wave w does chunk (slot w>>1, khalf w&1), sec = hi
  auto agg_w = [&](int e, int sbuf, int dbuf) {
    if (l31 < 24) {
      const int sec = hi;
      const int Mrow = l31;
      const int sbase = (sec * 4 + (w >> 1)) * 64 + ((w & 1) << 5);
      const unsigned short* xh = &XH[sbuf][e][0];
      f16x8 s = *reinterpret_cast<const f16x8*>(xh + (sbase + c_nbr2[Mrow][0]) * 8);
      #pragma unroll
      for (int m = 1; m < 5; ++m)             // sentinel 24 = zero pad row
        s += *reinterpret_cast<const f16x8*>(xh + (sbase + c_nbr2[Mrow][m]) * 8);
      s *= (_Float16)c_invdeg[Mrow];
      *reinterpret_cast<f16x8*>(&AGG[dbuf][e][0] + (sbase + Mrow) * 8) = s;
    }
  };

  // GEMM: 16 MFMA (setprio-wrapped), phase-local acc
  auto gemm = [&](int e, int buf) -> f32x16 {
    const unsigned short* ab = &AGG[buf][e][0];
    const unsigned short* xb = &XH[buf][e][0];
    f32x16 acc;
    #pragma unroll
    for (int p = 0; p < 8; ++p) {
      acc[2 * p]     = h2f_lo(bias_u[p]);
      acc[2 * p + 1] = h2f_hi(bias_u[p]);
    }
    __builtin_amdgcn_s_setprio(1);
    #pragma unroll
    for (int t = 0; t < 4; ++t)               // k 0..63: agg(x)
      acc = __builtin_amdgcn_mfma_f32_32x32x16_f16(
          W[t], *reinterpret_cast<const f16x8*>(ab + (t * 64 + l) * 8), acc, 0, 0, 0);
    #pragma unroll
    for (int t = 0; t < 4; ++t)               // k 64..127: x
      acc = __builtin_amdgcn_mfma_f32_32x32x16_f16(
          W[4 + t], *reinterpret_cast<const f16x8*>(xb + (t * 64 + l) * 8), acc, 0, 0, 0);
    #pragma unroll
    for (int t = 0; t < 4; ++t)               // k 128..191: agg(h)
      acc = __builtin_amdgcn_mfma_f32_32x32x16_f16(
          W[8 + t], *reinterpret_cast<const f16x8*>(ab + ((4 + t) * 64 + l) * 8), acc, 0, 0, 0);
    #pragma unroll
    for (int t = 0; t < 4; ++t)               // k 192..255: h
      acc = __builtin_amdgcn_mfma_f32_32x32x16_f16(
          W[12 + t], *reinterpret_cast<const f16x8*>(xb + ((4 + t) * 64 + l) * 8), acc, 0, 0, 0);
    __builtin_amdgcn_s_setprio(0);
    return acc;
  };

  // epilogue: rows l31<24, d = w*8 + 4*hi + u (contiguous) -> b64 writes
  auto epi = [&](const f32x16& acc, int e, int step, int wbuf) {
    if (l31 < 24) {
      float Ov[4], Hv[4];
      #pragma unroll
      for (int u = 0; u < 4; ++u) {
        float cv = creg[e * 4 + u];
        float I = sigm_(acc[4 * u + 0] + gwv[u] * cv);
        float F = sigm_(acc[4 * u + 1] + gwv[4 + u] * cv);
        float T = tanh_(acc[4 * u + 2]);
        float cn = F * cv + I * T;
        float O = sigm_(acc[4 * u + 3] + gwv[8 + u] * cn);
        Ov[u] = O;
        Hv[u] = O * tanh_(cn);
        creg[e * 4 + u] = cn;
      }
      uint2 ou, hu;
      ou.x = pkrtz(Ov[0], Ov[1]); ou.y = pkrtz(Ov[2], Ov[3]);
      hu.x = pkrtz(Hv[0], Hv[1]); hu.y = pkrtz(Hv[2], Hv[3]);
      unsigned short* xh = &XH[wbuf][e][0];
      const int base = (((w >> 1) * 64 + l31 + ((w & 1) << 5)) << 3) + 4 * hi;
      *reinterpret_cast<uint2*>(xh + base) = ou;          // x slot
      *reinterpret_cast<uint2*>(xh + 2048 + base) = hu;   // h slot
      if (step >= 12)
        *reinterpret_cast<uint2*>(
            obuf + (size_t)((n2 + e) * 12 + step - 12) * 1536 + l31 * 64 + w * 8 + 4 * hi) = ou;
    }
  };

  // ---- prologue ----------------------------------------------------------
  __syncthreads();                            // zero-init visible
  enc_to_x(src + ((size_t)n2 * 16 + 4) * 72,
           src + ((size_t)(n2 + 1) * 16 + 4) * 72, 0);
  __syncthreads();
  agg_w(0, 0, 0);
  agg_w(1, 0, 0);
  __syncthreads();

  int cur = 0;
  #pragma unroll 1
  for (int step = 0; step < 24; ++step) {
    if (step == 12) {                         // decode init: re-encode tgt[:,0]
      enc_to_x(tgt + (size_t)n2 * 864, tgt + (size_t)(n2 + 1) * 864, cur);
      __syncthreads();
      agg_w(0, cur, cur);                     // redo agg from fresh x
      agg_w(1, cur, cur);
      __syncthreads();
    }
    // ---- single-barrier step: per wave fully sequential, waves drift ----
    {
      f32x16 acc = gemm(0, cur);
      epi(acc, 0, step, cur ^ 1);
      agg_w(0, cur ^ 1, cur ^ 1);             // chunk-local: same-wave order
    }
    {
      f32x16 acc = gemm(1, cur);
      epi(acc, 1, step, cur ^ 1);
      agg_w(1, cur ^ 1, cur ^ 1);
    }
    __syncthreads();
    cur ^= 1;
  }
}

// ---------------------------------------------------------------------------
// dec: out[row][e] = O[row,:] . decW[:,e] + db[e]; rows = n*12+ts.
// block: 32 rows, 4 waves K-split (384 each), 3 col-tiles, LDS reduce.
// ---------------------------------------------------------------------------
__global__ __launch_bounds__(256) void dec4_kernel(
    const unsigned short* __restrict__ obuf,
    const unsigned short* __restrict__ Bdec,
    const float* __restrict__ db,
    float* __restrict__ out)
{
  __shared__ float part[4 * 3 * 64 * 16];    // 48 KB
  const int tid = threadIdx.x;
  const int w = tid >> 6, l = tid & 63;
  const int l31 = l & 31, hi = l >> 5;
  const int r0 = blockIdx.x * 32;

  f32x16 a0, a1, a2;
  #pragma unroll
  for (int r = 0; r < 16; ++r) { a0[r] = 0.f; a1[r] = 0.f; a2[r] = 0.f; }

  const unsigned short* Ap = obuf + (size_t)(r0 + l31) * 1536 + hi * 8;
  #pragma unroll 4
  for (int tt = 0; tt < 24; ++tt) {
    int kt = w * 24 + tt;
    f16x8 av = *reinterpret_cast<const f16x8*>(Ap + kt * 16);
    f16x8 b0 = *reinterpret_cast<const f16x8*>(Bdec + ((0 * 96 + kt) * 64 + l) * 8);
    f16x8 b1 = *reinterpret_cast<const f16x8*>(Bdec + ((1 * 96 + kt) * 64 + l) * 8);
    f16x8 b2 = *reinterpret_cast<const f16x8*>(Bdec + ((2 * 96 + kt) * 64 + l) * 8);
    a0 = __builtin_amdgcn_mfma_f32_32x32x16_f16(av, b0, a0, 0, 0, 0);
    a1 = __builtin_amdgcn_mfma_f32_32x32x16_f16(av, b1, a1, 0, 0, 0);
    a2 = __builtin_amdgcn_mfma_f32_32x32x16_f16(av, b2, a2, 0, 0, 0);
  }
  #pragma unroll
  for (int r = 0; r < 16; ++r) {
    part[((w * 3 + 0) * 64 + l) * 16 + r] = a0[r];
    part[((w * 3 + 1) * 64 + l) * 16 + r] = a1[r];
    part[((w * 3 + 2) * 64 + l) * 16 + r] = a2[r];
  }
  __syncthreads();

  // reduce 4 K-partials; thread -> (row = tid>>3, e = (tid&7)*12 + 0..11)
  int row = tid >> 3;
  int hi2 = (row >> 2) & 1;
  int rr = 4 * (row >> 3) + (row & 3);
  #pragma unroll
  for (int ei = 0; ei < 12; ++ei) {
    int e = (tid & 7) * 12 + ei;
    if (e < 72) {
      int nt = e >> 5, e32 = e & 31;
      float s = db[e];
      #pragma unroll
      for (int w2 = 0; w2 < 4; ++w2)
        s += part[((w2 * 3 + nt) * 64 + e32 + 32 * hi2) * 16 + rr];
      out[(size_t)(r0 + row) * 72 + e] = s;
    }
  }
}

// ---------------------------------------------------------------------------
extern "C" void kernel_launch(void* const* d_in, const int* in_sizes, int n_in,
                              void* d_out, int out_size, void* d_ws, size_t ws_size,
                              hipStream_t stream) {
  const float* src  = (const float*)d_in[0];   // [1024,16,72]
  const float* tgt  = (const float*)d_in[1];   // [1024,12,72]
  const float* encW = (const float*)d_in[2];   // [3,64]
  const float* encb = (const float*)d_in[3];   // [64]
  const float* sWl  = (const float*)d_in[4];   // [8,64,64]
  const float* sbl  = (const float*)d_in[5];   // [8,64]
  const float* sWr  = (const float*)d_in[6];   // [8,64,64]
  const float* gw   = (const float*)d_in[7];   // [3,1,64]
  const float* gb   = (const float*)d_in[8];   // [4,1,64]
  const float* dW   = (const float*)d_in[9];   // [1536,72]
  const float* db   = (const float*)d_in[10];  // [72]
  float* out = (float*)d_out;

  unsigned short* obuf  = (unsigned short*)d_ws;        // 12288*1536 fp16
  unsigned short* Wfrag = obuf + (size_t)12288 * 1536;  // 65536 fp16
  unsigned short* Bdec  = Wfrag + 65536;                // 147456 fp16
  float*          biasv = (float*)(Bdec + 147456);      // 256 f32

  prep5_kernel<<<833, 256, 0, stream>>>(sWl, sbl, sWr, gb, dW, Wfrag, biasv, Bdec);
  mono12_kernel<<<512, 512, 0, stream>>>(src, tgt, encW, encb, gw, Wfrag, biasv, obuf);
  dec4_kernel<<<384, 256, 0, stream>>>(obuf, Bdec, db, out);
}

// Round 14
// 167.454 us; speedup vs baseline: 1.5000x; 1.0876x over previous
//
#include <hip/hip_runtime.h>

// ---------------------------------------------------------------------------
// SAGE-GCN LSTM, N=1024, J=24, D=64.  R14 = R12 schedule + exp2-prescale only
// (R13's NaN isolated: revert split-epi, drop __ocml symbol; exp2 via inline
//  asm v_exp_f32 which has zero link/semantics risk).
//  mono: 512 blocks (2/CU) x 512 thr (8 waves), 2 elems/block, 24 cells.
//   ONE barrier per step; per wave sequentially {gemm(e)->epi(e)->agg(e,next)}
//   for e=0,1 (chunk-ownership makes epi->agg same-wave ordered). setprio(1)
//   around MFMA chains. Phase-local acc (no cross-barrier acc).
//   PRESCALE: W/bias cols for I,F,O scaled by -log2e (sigmoid negation folds
//   away), T by +2*log2e; gw by -log2e. Activations: sigma = rcp(1+exp2(y)),
//   tanh = 1-2*rcp(1+exp2(y')), raw v_exp_f32.
//  dec: fp16 MFMA, 4-wave K-split + LDS reduce.  prep: weight packing.
// ---------------------------------------------------------------------------

typedef _Float16 f16x8 __attribute__((ext_vector_type(8)));
typedef float f32x16 __attribute__((ext_vector_type(16)));

// neighbor table with sentinel 24 (zero pad row) instead of -1: always 5 reads
__constant__ int c_nbr2[24][5] = {
  {0,1,2,3,24},  {1,0,4,24,24}, {2,0,5,24,24}, {3,0,6,24,24},
  {4,1,7,24,24}, {5,2,8,24,24}, {6,3,9,24,24}, {7,4,10,24,24},
  {8,5,11,24,24},{9,6,12,13,14},{10,7,24,24,24},{11,8,24,24,24},
  {12,9,15,24,24},{13,9,16,24,24},{14,9,17,24,24},{15,12,24,24,24},
  {16,13,18,24,24},{17,14,19,24,24},{18,16,20,24,24},{19,17,21,24,24},
  {20,18,22,24,24},{21,19,23,24,24},{22,20,24,24,24},{23,21,24,24,24}
};
__constant__ float c_invdeg[24] = {
  0.25f, 1.f/3.f, 1.f/3.f, 1.f/3.f, 1.f/3.f, 1.f/3.f, 1.f/3.f, 1.f/3.f,
  1.f/3.f, 0.2f, 0.5f, 0.5f, 1.f/3.f, 1.f/3.f, 1.f/3.f, 0.5f,
  1.f/3.f, 1.f/3.f, 1.f/3.f, 1.f/3.f, 1.f/3.f, 1.f/3.f, 0.5f, 0.5f
};

#define LOG2E  1.442695041f
#define LOG2E2 2.885390082f

__device__ __forceinline__ unsigned short f2h(float f) {
  _Float16 h = (_Float16)f;
  return __builtin_bit_cast(unsigned short, h);
}
__device__ __forceinline__ unsigned pk2h(float a, float b) {
  return (unsigned)f2h(a) | ((unsigned)f2h(b) << 16);
}
__device__ __forceinline__ unsigned pkrtz(float lo, float hi) {  // 1 inst
  unsigned r;
  asm("v_cvt_pkrtz_f16_f32 %0, %1, %2" : "=v"(r) : "v"(lo), "v"(hi));
  return r;
}
__device__ __forceinline__ float h2f_lo(unsigned u) {
  return (float)__builtin_bit_cast(_Float16, (unsigned short)(u & 0xffff));
}
__device__ __forceinline__ float h2f_hi(unsigned u) {
  return (float)__builtin_bit_cast(_Float16, (unsigned short)(u >> 16));
}
__device__ __forceinline__ float vexp2(float x) {                // raw v_exp_f32
  float r;
  asm("v_exp_f32 %0, %1" : "=v"(r) : "v"(x));
  return r;
}
// y = (-log2e)-prescaled pre-activation: sigma(x) = rcp(1 + 2^(-x*log2e))
__device__ __forceinline__ float sigm2_(float y) {
  return __builtin_amdgcn_rcpf(1.0f + vexp2(y));
}
// y = (+2*log2e)-prescaled pre-activation: tanh(x) = 1 - 2*rcp(1 + 2^(2x*log2e))
__device__ __forceinline__ float tanh2_(float y) {
  return 1.0f - 2.0f * __builtin_amdgcn_rcpf(1.0f + vexp2(y));
}
// c true-scale
__device__ __forceinline__ float tanhc_(float c) {
  return 1.0f - 2.0f * __builtin_amdgcn_rcpf(1.0f + vexp2(c * LOG2E2));
}

// ---------------------------------------------------------------------------
// prep: Wfrag (fp16, A-frag layout, PRESCALED), biasv f32 (prescaled), Bdec.
//  m32 -> (g, d): g = m32 & 3; tq = m32>>2; d = mt*8 + (tq>>1) + 4*(tq&1).
//  scale(g): I,F,O (g 0,1,3) -> -log2e ; T (g==2) -> +2*log2e.
//  k = t*16 + (lane>>5)*8 + i; q=k>>6: q0 Wl[2g], q1 Wr[2g], q2 Wl[2g+1], q3 Wr[2g+1]
// ---------------------------------------------------------------------------
__global__ void prep7_kernel(const float* __restrict__ sWl, const float* __restrict__ sbl,
                             const float* __restrict__ sWr, const float* __restrict__ gb,
                             const float* __restrict__ dW,
                             unsigned short* __restrict__ Wfrag,
                             float* __restrict__ biasv,
                             unsigned short* __restrict__ Bdec)
{
  int id = blockIdx.x * 256 + threadIdx.x;          // 213248 total
  if (id < 65536) {                                  // Wfrag [mt][t][lane][8]
    int i = id & 7, l = (id >> 3) & 63, t = (id >> 9) & 15, mt = id >> 13;
    int m32 = l & 31;
    int g = m32 & 3, tq = m32 >> 2;
    int d = mt * 8 + (tq >> 1) + 4 * (tq & 1);
    int k = t * 16 + ((l >> 5) << 3) + i;
    int q = k >> 6, kk = k & 63;
    const float* Ws = (q & 1) ? sWr : sWl;
    float sc = (g == 2) ? LOG2E2 : -LOG2E;
    Wfrag[id] = f2h(sc * Ws[((2 * g + (q >> 1)) * 64 + kk) * 64 + d]);
  } else if (id < 65792) {                           // biasv[mt*32 + m32]
    int c = id - 65536;
    int mt = c >> 5, m32 = c & 31;
    int g = m32 & 3, tq = m32 >> 2;
    int d = mt * 8 + (tq >> 1) + 4 * (tq & 1);
    float sc = (g == 2) ? LOG2E2 : -LOG2E;
    biasv[c] = sc * (sbl[(2 * g) * 64 + d] + sbl[(2 * g + 1) * 64 + d] + gb[g * 64 + d]);
  } else {                                           // Bdec [nt][96 t][lane][8]
    int p = id - 65792;                              // < 147456
    int i = p & 7, l = (p >> 3) & 63;
    int rem = p >> 9;                                // nt*96 + t
    int nt = rem / 96, t = rem - nt * 96;
    int e = nt * 32 + (l & 31);
    int k = t * 16 + ((l >> 5) << 3) + i;
    Bdec[p] = (e < 72) ? f2h(dW[k * 72 + e]) : (unsigned short)0;
  }
}

// ---------------------------------------------------------------------------
// mono: all 24 cells for TWO batch elements per block.  64 KB LDS, 2 blk/CU.
// ---------------------------------------------------------------------------
__global__ __launch_bounds__(512, 4) void mono14_kernel(
    const float* __restrict__ src, const float* __restrict__ tgt,
    const float* __restrict__ encW, const float* __restrict__ encb,
    const float* __restrict__ gw,
    const unsigned short* __restrict__ Wfrag,
    const float* __restrict__ biasv,
    unsigned short* __restrict__ obuf)
{
  // frag layout: addr (u16) = (slot*64 + row + khalf*32)*8 + i, row<24, pad..31
  __shared__ __align__(16) unsigned short AGG[2][2][8 * 64 * 8];  // 32 KB [buf][elem]
  __shared__ __align__(16) unsigned short XH[2][2][8 * 64 * 8];   // 32 KB [buf][elem]

  const int tid = threadIdx.x;
  const int n2 = blockIdx.x * 2;
  const int w = tid >> 6, l = tid & 63;      // wave = M-tile mt = chunk owner
  const int l31 = l & 31, hi = l >> 5;

  // ---- persistent W: 1 M-tile x 16 k-steps = 64 VGPR ---------------------
  f16x8 W[16];
  {
    const f16x8* p0 = reinterpret_cast<const f16x8*>(Wfrag) + (w * 16) * 64 + l;
    #pragma unroll
    for (int t = 0; t < 16; ++t) W[t] = p0[t * 64];
  }
  // ---- bias (fp16-packed per acc-reg pair), gate_w scalars (prescaled) ---
  unsigned bias_u[8];
  #pragma unroll
  for (int p = 0; p < 8; ++p) {
    int r0 = 2 * p, r1 = 2 * p + 1;
    int m0 = (r0 & 3) + 8 * (r0 >> 2) + 4 * hi;
    int m1 = (r1 & 3) + 8 * (r1 >> 2) + 4 * hi;
    bias_u[p] = pk2h(biasv[w * 32 + m0], biasv[w * 32 + m1]);
  }
  float gwv[12];                             // d = w*8 + 4*hi + u ; * -log2e
  #pragma unroll
  for (int g = 0; g < 3; ++g)
    #pragma unroll
    for (int u = 0; u < 4; ++u)
      gwv[g * 4 + u] = -LOG2E * gw[g * 64 + w * 8 + 4 * hi + u];

  float creg[8];                             // c-state: [e][u], true scale
  #pragma unroll
  for (int i = 0; i < 8; ++i) creg[i] = 0.0f;

  // ---- zero init XH + AGG (both bufs: h=0, pad rows) ---------------------
  {
    uint4 z = make_uint4(0, 0, 0, 0);
    uint4* xz = reinterpret_cast<uint4*>(&XH[0][0][0]);
    #pragma unroll
    for (int i = 0; i < 4; ++i) xz[tid + i * 512] = z;   // 32 KB
    uint4* az = reinterpret_cast<uint4*>(&AGG[0][0][0]);
    #pragma unroll
    for (int i = 0; i < 4; ++i) az[tid + i * 512] = z;   // 32 KB
  }

  // encoder -> x-sections (slots 0-3) of XH[buf][e]
  auto enc_to_x = [&](const float* f0, const float* f1, int buf) {
    #pragma unroll
    for (int ii = 0; ii < 6; ++ii) {
      int idx = tid + ii * 512;               // < 3072
      int e = (idx >= 1536) ? 1 : 0;
      int r = idx - e * 1536;
      int j = r >> 6, d = r & 63;
      const float* f = (e ? f1 : f0) + j * 3;
      float v = encb[d] + f[0] * encW[d] + f[1] * encW[64 + d] + f[2] * encW[128 + d];
      XH[buf][e][((d >> 4) * 64 + j + ((d >> 3) & 1) * 32) * 8 + (d & 7)] =
          f2h(fmaxf(v, 0.0f));
    }
  };

  // wave-owned aggregation: wave w does chunk (slot w>>1, khalf w&1), sec = hi
  auto agg_w = [&](int e, int sbuf, int dbuf) {
    if (l31 < 24) {
      const int sec = hi;
      const int Mrow = l31;
      const int sbase = (sec * 4 + (w >> 1)) * 64 + ((w & 1) << 5);
      const unsigned short* xh = &XH[sbuf][e][0];
      f16x8 s = *reinterpret_cast<const f16x8*>(xh + (sbase + c_nbr2[Mrow][0]) * 8);
      #pragma unroll
      for (int m = 1; m < 5; ++m)             // sentinel 24 = zero pad row
        s += *reinterpret_cast<const f16x8*>(xh + (sbase + c_nbr2[Mrow][m]) * 8);
      s *= (_Float16)c_invdeg[Mrow];
      *reinterpret_cast<f16x8*>(&AGG[dbuf][e][0] + (sbase + Mrow) * 8) = s;
    }
  };

  // GEMM: 16 MFMA (setprio-wrapped), phase-local acc
  auto gemm = [&](int e, int buf) -> f32x16 {
    const unsigned short* ab = &AGG[buf][e][0];
    const unsigned short* xb = &XH[buf][e][0];
    f32x16 acc;
    #pragma unroll
    for (int p = 0; p < 8; ++p) {
      acc[2 * p]     = h2f_lo(bias_u[p]);
      acc[2 * p + 1] = h2f_hi(bias_u[p]);
    }
    __builtin_amdgcn_s_setprio(1);
    #pragma unroll
    for (int t = 0; t < 4; ++t)               // k 0..63: agg(x)
      acc = __builtin_amdgcn_mfma_f32_32x32x16_f16(
          W[t], *reinterpret_cast<const f16x8*>(ab + (t * 64 + l) * 8), acc, 0, 0, 0);
    #pragma unroll
    for (int t = 0; t < 4; ++t)               // k 64..127: x
      acc = __builtin_amdgcn_mfma_f32_32x32x16_f16(
          W[4 + t], *reinterpret_cast<const f16x8*>(xb + (t * 64 + l) * 8), acc, 0, 0, 0);
    #pragma unroll
    for (int t = 0; t < 4; ++t)               // k 128..191: agg(h)
      acc = __builtin_amdgcn_mfma_f32_32x32x16_f16(
          W[8 + t], *reinterpret_cast<const f16x8*>(ab + ((4 + t) * 64 + l) * 8), acc, 0, 0, 0);
    #pragma unroll
    for (int t = 0; t < 4; ++t)               // k 192..255: h
      acc = __builtin_amdgcn_mfma_f32_32x32x16_f16(
          W[12 + t], *reinterpret_cast<const f16x8*>(xb + ((4 + t) * 64 + l) * 8), acc, 0, 0, 0);
    __builtin_amdgcn_s_setprio(0);
    return acc;
  };

  // epilogue (full, R12-style): rows l31<24, d = w*8 + 4*hi + u -> b64 writes
  auto epi = [&](const f32x16& acc, int e, int step, int wbuf) {
    if (l31 < 24) {
      float Ov[4], Hv[4];
      #pragma unroll
      for (int u = 0; u < 4; ++u) {
        float cv = creg[e * 4 + u];
        float I = sigm2_(acc[4 * u + 0] + gwv[u] * cv);
        float F = sigm2_(acc[4 * u + 1] + gwv[4 + u] * cv);
        float T = tanh2_(acc[4 * u + 2]);
        float cn = F * cv + I * T;
        float O = sigm2_(acc[4 * u + 3] + gwv[8 + u] * cn);
        Ov[u] = O;
        Hv[u] = O * tanhc_(cn);
        creg[e * 4 + u] = cn;
      }
      uint2 ou, hu;
      ou.x = pkrtz(Ov[0], Ov[1]); ou.y = pkrtz(Ov[2], Ov[3]);
      hu.x = pkrtz(Hv[0], Hv[1]); hu.y = pkrtz(Hv[2], Hv[3]);
      unsigned short* xh = &XH[wbuf][e][0];
      const int base = (((w >> 1) * 64 + l31 + ((w & 1) << 5)) << 3) + 4 * hi;
      *reinterpret_cast<uint2*>(xh + base) = ou;          // x slot
      *reinterpret_cast<uint2*>(xh + 2048 + base) = hu;   // h slot
      if (step >= 12)
        *reinterpret_cast<uint2*>(
            obuf + (size_t)((n2 + e) * 12 + step - 12) * 1536 + l31 * 64 + w * 8 + 4 * hi) = ou;
    }
  };

  // ---- prologue ----------------------------------------------------------
  __syncthreads();                            // zero-init visible
  enc_to_x(src + ((size_t)n2 * 16 + 4) * 72,
           src + ((size_t)(n2 + 1) * 16 + 4) * 72, 0);
  __syncthreads();
  agg_w(0, 0, 0);
  agg_w(1, 0, 0);
  __syncthreads();

  int cur = 0;
  #pragma unroll 1
  for (int step = 0; step < 24; ++step) {
    if (step == 12) {                         // decode init: re-encode tgt[:,0]
      enc_to_x(tgt + (size_t)n2 * 864, tgt + (size_t)(n2 + 1) * 864, cur);
      __syncthreads();
      agg_w(0, cur, cur);                     // redo agg from fresh x
      agg_w(1, cur, cur);
      __syncthreads();
    }
    // ---- single-barrier step: per wave fully sequential, waves drift ----
    {
      f32x16 acc = gemm(0, cur);
      epi(acc, 0, step, cur ^ 1);
      agg_w(0, cur ^ 1, cur ^ 1);             // chunk-local: same-wave order
    }
    {
      f32x16 acc = gemm(1, cur);
      epi(acc, 1, step, cur ^ 1);
      agg_w(1, cur ^ 1, cur ^ 1);
    }
    __syncthreads();
    cur ^= 1;
  }
}

// ---------------------------------------------------------------------------
// dec: out[row][e] = O[row,:] . decW[:,e] + db[e]; rows = n*12+ts.
// block: 32 rows, 4 waves K-split (384 each), 3 col-tiles, LDS reduce.
// ---------------------------------------------------------------------------
__global__ __launch_bounds__(256) void dec4_kernel(
    const unsigned short* __restrict__ obuf,
    const unsigned short* __restrict__ Bdec,
    const float* __restrict__ db,
    float* __restrict__ out)
{
  __shared__ float part[4 * 3 * 64 * 16];    // 48 KB
  const int tid = threadIdx.x;
  const int w = tid >> 6, l = tid & 63;
  const int l31 = l & 31, hi = l >> 5;
  const int r0 = blockIdx.x * 32;

  f32x16 a0, a1, a2;
  #pragma unroll
  for (int r = 0; r < 16; ++r) { a0[r] = 0.f; a1[r] = 0.f; a2[r] = 0.f; }

  const unsigned short* Ap = obuf + (size_t)(r0 + l31) * 1536 + hi * 8;
  #pragma unroll 4
  for (int tt = 0; tt < 24; ++tt) {
    int kt = w * 24 + tt;
    f16x8 av = *reinterpret_cast<const f16x8*>(Ap + kt * 16);
    f16x8 b0 = *reinterpret_cast<const f16x8*>(Bdec + ((0 * 96 + kt) * 64 + l) * 8);
    f16x8 b1 = *reinterpret_cast<const f16x8*>(Bdec + ((1 * 96 + kt) * 64 + l) * 8);
    f16x8 b2 = *reinterpret_cast<const f16x8*>(Bdec + ((2 * 96 + kt) * 64 + l) * 8);
    a0 = __builtin_amdgcn_mfma_f32_32x32x16_f16(av, b0, a0, 0, 0, 0);
    a1 = __builtin_amdgcn_mfma_f32_32x32x16_f16(av, b1, a1, 0, 0, 0);
    a2 = __builtin_amdgcn_mfma_f32_32x32x16_f16(av, b2, a2, 0, 0, 0);
  }
  #pragma unroll
  for (int r = 0; r < 16; ++r) {
    part[((w * 3 + 0) * 64 + l) * 16 + r] = a0[r];
    part[((w * 3 + 1) * 64 + l) * 16 + r] = a1[r];
    part[((w * 3 + 2) * 64 + l) * 16 + r] = a2[r];
  }
  __syncthreads();

  // reduce 4 K-partials; thread -> (row = tid>>3, e = (tid&7)*12 + 0..11)
  int row = tid >> 3;
  int hi2 = (row >> 2) & 1;
  int rr = 4 * (row >> 3) + (row & 3);
  #pragma unroll
  for (int ei = 0; ei < 12; ++ei) {
    int e = (tid & 7) * 12 + ei;
    if (e < 72) {
      int nt = e >> 5, e32 = e & 31;
      float s = db[e];
      #pragma unroll
      for (int w2 = 0; w2 < 4; ++w2)
        s += part[((w2 * 3 + nt) * 64 + e32 + 32 * hi2) * 16 + rr];
      out[(size_t)(r0 + row) * 72 + e] = s;
    }
  }
}

// ---------------------------------------------------------------------------
extern "C" void kernel_launch(void* const* d_in, const int* in_sizes, int n_in,
                              void* d_out, int out_size, void* d_ws, size_t ws_size,
                              hipStream_t stream) {
  const float* src  = (const float*)d_in[0];   // [1024,16,72]
  const float* tgt  = (const float*)d_in[1];   // [1024,12,72]
  const float* encW = (const float*)d_in[2];   // [3,64]
  const float* encb = (const float*)d_in[3];   // [64]
  const float* sWl  = (const float*)d_in[4];   // [8,64,64]
  const float* sbl  = (const float*)d_in[5];   // [8,64]
  const float* sWr  = (const float*)d_in[6];   // [8,64,64]
  const float* gw   = (const float*)d_in[7];   // [3,1,64]
  const float* gb   = (const float*)d_in[8];   // [4,1,64]
  const float* dW   = (const float*)d_in[9];   // [1536,72]
  const float* db   = (const float*)d_in[10];  // [72]
  float* out = (float*)d_out;

  unsigned short* obuf  = (unsigned short*)d_ws;        // 12288*1536 fp16
  unsigned short* Wfrag = obuf + (size_t)12288 * 1536;  // 65536 fp16
  unsigned short* Bdec  = Wfrag + 65536;                // 147456 fp16
  float*          biasv = (float*)(Bdec + 147456);      // 256 f32

  prep7_kernel<<<833, 256, 0, stream>>>(sWl, sbl, sWr, gb, dW, Wfrag, biasv, Bdec);
  mono14_kernel<<<512, 512, 0, stream>>>(src, tgt, encW, encb, gw, Wfrag, biasv, obuf);
  dec4_kernel<<<384, 256, 0, stream>>>(obuf, Bdec, db, out);
}